// Round 10
// baseline (363.353 us; speedup 1.0000x reference)
//
#include <hip/hip_runtime.h>

typedef unsigned short u16;
typedef unsigned int u32;
typedef unsigned long long u64;
typedef __attribute__((ext_vector_type(8))) short bf16x8;
typedef __attribute__((ext_vector_type(4))) float f32x4;

#define NB 2
#define NS 2048
#define NDM 1024
#define NH 16

#define MFMA_B16(a, b, c) __builtin_amdgcn_mfma_f32_16x16x32_bf16(a, b, c, 0, 0, 0)

__device__ __forceinline__ u16 f2bf(float f) {
  union { float f; unsigned u; } v; v.f = f;
  return (u16)((v.u + 0x7fffu + ((v.u >> 16) & 1u)) >> 16);
}
__device__ __forceinline__ float bf2f(u16 h) {
  union { float f; unsigned u; } v; v.u = ((u32)h) << 16; return v.f;
}

// fused cast of Q,K,V -> bf16 (3 x 1048576 float4 quads)
__global__ __launch_bounds__(256) void cast3_bf16(const float* __restrict__ a,
                                                  const float* __restrict__ b,
                                                  const float* __restrict__ c,
                                                  u16* __restrict__ oa, u16* __restrict__ ob,
                                                  u16* __restrict__ oc) {
  int i = blockIdx.x * 256 + threadIdx.x;
  const float* src; u16* dst; int j;
  if (i < 1048576) { src = a; dst = oa; j = i; }
  else if (i < 2097152) { src = b; dst = ob; j = i - 1048576; }
  else { src = c; dst = oc; j = i - 2097152; }
  const float4 v = reinterpret_cast<const float4*>(src)[j];
  ushort4 o; o.x = f2bf(v.x); o.y = f2bf(v.y); o.z = f2bf(v.z); o.w = f2bf(v.w);
  reinterpret_cast<ushort4*>(dst)[j] = o;
}

// fused transpose of the 4 weight matrices: f32 [1024][1024] -> bf16 transposed
struct TW4 { const float* in[4]; u16* out[4]; };
__global__ __launch_bounds__(256) void transpose_w4(TW4 tw) {
  __shared__ float tile[32][33];
  const float* in = tw.in[blockIdx.z];
  u16* out = tw.out[blockIdx.z];
  int bx = blockIdx.x, by = blockIdx.y;
  int x = threadIdx.x & 31, y0 = threadIdx.x >> 5;
#pragma unroll
  for (int i = 0; i < 4; i++) {
    int y = y0 + i * 8;
    tile[y][x] = in[(by * 32 + y) * NDM + bx * 32 + x];
  }
  __syncthreads();
#pragma unroll
  for (int i = 0; i < 4; i++) {
    int y = y0 + i * 8;
    out[(bx * 32 + y) * NDM + by * 32 + x] = f2bf(tile[x][y]);
  }
}

// ---- mask [B,S,S] -> bitmask, 1 bit/col ----
__global__ __launch_bounds__(256) void mask2bits(const u32* __restrict__ mask, u32* __restrict__ mb) {
  int idx = blockIdx.x * 256 + threadIdx.x;
  u32 mw0 = mask[threadIdx.x & 63];
  bool floatmode = (__ballot(mw0 == 0x3F800000u) != 0ull);
  bool bytemode = !floatmode && (__ballot((mw0 >> 8) != 0u) != 0ull);
  int row = idx >> 6;
  int wword = idx & 63;
  u32 bits = 0;
  if (!bytemode) {
    const uint4* p = reinterpret_cast<const uint4*>(mask + (size_t)row * 2048 + wword * 32);
#pragma unroll
    for (int i = 0; i < 8; i++) {
      uint4 v = p[i];
      bits |= (v.x ? 1u : 0u) << (i * 4 + 0);
      bits |= (v.y ? 1u : 0u) << (i * 4 + 1);
      bits |= (v.z ? 1u : 0u) << (i * 4 + 2);
      bits |= (v.w ? 1u : 0u) << (i * 4 + 3);
    }
  } else {
    const uint4* p = reinterpret_cast<const uint4*>(
        reinterpret_cast<const unsigned char*>(mask) + (size_t)row * 2048 + wword * 32);
#pragma unroll
    for (int i = 0; i < 2; i++) {
      uint4 v = p[i];
      u32 wsv[4] = {v.x, v.y, v.z, v.w};
#pragma unroll
      for (int j = 0; j < 4; j++)
#pragma unroll
        for (int kq = 0; kq < 4; kq++)
          bits |= ((((wsv[j] >> (kq * 8)) & 0xffu) != 0u) ? 1u : 0u) << (i * 16 + j * 4 + kq);
    }
  }
  mb[idx] = bits;
}

// ---- 128x128-tile bf16 GEMM, B^T layout ----
struct GArgs { const u16* X; const u16* W; const float* bias; void* out; int mode; float scale; };

__global__ __launch_bounds__(256, 2) void gemm_bt(GArgs g0, GArgs g1, GArgs g2) {
  GArgs ga = (blockIdx.z == 0) ? g0 : (blockIdx.z == 1 ? g1 : g2);
  const int K = 1024, N = 1024;
  __shared__ u16 As[128 * 32];
  __shared__ u16 Bs[128 * 32];
  const int t = threadIdx.x, w = t >> 6, l = t & 63;
  const int m0 = blockIdx.x * 128, n0 = blockIdx.y * 128;
  const int wm = (w >> 1) * 64, wn = (w & 1) * 64;
  const f32x4 fz = {0.f, 0.f, 0.f, 0.f};
  f32x4 acc[4][4];
#pragma unroll
  for (int i = 0; i < 4; i++)
#pragma unroll
    for (int j = 0; j < 4; j++) acc[i][j] = fz;

  for (int k0 = 0; k0 < K; k0 += 32) {
#pragma unroll
    for (int i = 0; i < 2; i++) {
      int idx = i * 256 + w * 64 + l;
      int r = idx >> 2, c = (idx & 3) * 8;
      __builtin_amdgcn_global_load_lds(
          reinterpret_cast<const unsigned*>(ga.X + (size_t)(m0 + r) * K + k0 + c),
          reinterpret_cast<unsigned*>(&As[(i * 256 + w * 64) * 8]), 16, 0, 0);
      __builtin_amdgcn_global_load_lds(
          reinterpret_cast<const unsigned*>(ga.W + (size_t)(n0 + r) * K + k0 + c),
          reinterpret_cast<unsigned*>(&Bs[(i * 256 + w * 64) * 8]), 16, 0, 0);
    }
    __syncthreads();
    bf16x8 af[4], bfr[4];
#pragma unroll
    for (int mt = 0; mt < 4; mt++)
      af[mt] = *reinterpret_cast<const bf16x8*>(&As[(wm + mt * 16 + (l & 15)) * 32 + (l >> 4) * 8]);
#pragma unroll
    for (int nt = 0; nt < 4; nt++)
      bfr[nt] = *reinterpret_cast<const bf16x8*>(&Bs[(wn + nt * 16 + (l & 15)) * 32 + (l >> 4) * 8]);
#pragma unroll
    for (int mt = 0; mt < 4; mt++)
#pragma unroll
      for (int nt = 0; nt < 4; nt++)
        acc[mt][nt] = MFMA_B16(af[mt], bfr[nt], acc[mt][nt]);
    __syncthreads();
  }

#pragma unroll
  for (int nt = 0; nt < 4; nt++) {
    int n = n0 + wn + nt * 16 + (l & 15);
    float bias = ga.bias[n];
#pragma unroll
    for (int mt = 0; mt < 4; mt++) {
      int mb = m0 + wm + mt * 16 + ((l >> 4) << 2);
#pragma unroll
      for (int r = 0; r < 4; r++) {
        int m = mb + r;
        float v = (acc[mt][nt][r] + bias) * ga.scale;
        if (ga.mode == 2) {
          reinterpret_cast<float*>(ga.out)[(size_t)m * N + n] = v;
        } else {
          int b = m >> 11, s = m & 2047, h = n >> 6, d = n & 63;
          if (ga.mode == 0)
            reinterpret_cast<u16*>(ga.out)[(((size_t)(b * NH + h) * NS + s) << 6) + d] = f2bf(v);
          else
            reinterpret_cast<u16*>(ga.out)[((size_t)(b * NH + h) * 64 + d) * NS + s] = f2bf(v);
        }
      }
    }
  }
}

// ---- attention: KVBLK=64, K+V LDS double-buffered (stride-64 XOR swizzle on both sides),
// masks (u64) register-prefetched 1 tile ahead, Ps stride-64 XOR-swizzled (8KB), counted vmcnt.
// LDS = 16K(K) + 16K(V) + 8K(Ps) = 40960 B -> exactly 4 blocks/CU. 32 barriers per pass. ----
__global__ __launch_bounds__(256, 4) void attn_kernel(
    const u16* __restrict__ qh, const u16* __restrict__ kh, const u16* __restrict__ vT,
    const u32* __restrict__ mb, float* __restrict__ attn, u16* __restrict__ ctx) {
  __shared__ u16 Ks[2][64 * 64];
  __shared__ u16 Vs[2][64 * 64];
  __shared__ u16 Ps[4][16 * 64];
  const int tid = threadIdx.x, w = tid >> 6, l = tid & 63;
  int id = blockIdx.x;
  int wgid = (id & 7) * 128 + (id >> 3);   // XCD-chunked bijective swizzle (1024 % 8 == 0)
  int qt = wgid & 31, pr = wgid >> 5;
  int h = pr & 15, b = pr >> 4;
  const size_t head = (size_t)b * NH + h;
  const u16* qp = qh + head * NS * 64;
  const u16* kp = kh + head * NS * 64;
  const u16* vp = vT + head * 64 * NS;
  const int qr0 = qt * 64 + w * 16;
  const int lo = l & 15, hi = l >> 4;
  const int rbase = hi << 2;
  const f32x4 fz = {0.f, 0.f, 0.f, 0.f};

  bf16x8 aq0, aq1;
  {
    const u16* p = qp + (size_t)(qr0 + lo) * 64 + hi * 8;
    aq0 = *reinterpret_cast<const bf16x8*>(p);
    aq1 = *reinterpret_cast<const bf16x8*>(p + 32);
  }
  const u64* mrow = reinterpret_cast<const u64*>(mb) + ((size_t)b * NS + qr0 + rbase) * 32;

  // staging thread->element maps (per op i: 32 rows), pre-swizzled global sources (rule #21)
  const int st_r = tid >> 3, st_c = tid & 7;              // local row (0..31 per op), chunk
  const u16* ksrc0 = kp + (size_t)st_r * 64 + ((st_c ^ (st_r & 7)) * 8);
  const u16* vsrc0 = vp + (size_t)st_r * NS + ((st_c ^ (st_r & 7)) * 8);
  const int sx = lo & 7;                                  // read-side XOR (row&7 where row=..+lo)

#define STAGE_K(tt)                                                                     \
  {                                                                                     \
    __builtin_amdgcn_global_load_lds(                                                   \
        reinterpret_cast<const unsigned*>(ksrc0 + (size_t)(tt) * 4096),                 \
        reinterpret_cast<unsigned*>(&Ks[(tt) & 1][w * 512]), 16, 0, 0);                 \
    __builtin_amdgcn_global_load_lds(                                                   \
        reinterpret_cast<const unsigned*>(ksrc0 + (size_t)(tt) * 4096 + 32 * 64),       \
        reinterpret_cast<unsigned*>(&Ks[(tt) & 1][2048 + w * 512]), 16, 0, 0);          \
  }
#define STAGE_V(tt)                                                                     \
  {                                                                                     \
    __builtin_amdgcn_global_load_lds(                                                   \
        reinterpret_cast<const unsigned*>(vsrc0 + (size_t)(tt) * 64),                   \
        reinterpret_cast<unsigned*>(&Vs[(tt) & 1][w * 512]), 16, 0, 0);                 \
    __builtin_amdgcn_global_load_lds(                                                   \
        reinterpret_cast<const unsigned*>(vsrc0 + (size_t)32 * NS + (size_t)(tt) * 64), \
        reinterpret_cast<unsigned*>(&Vs[(tt) & 1][2048 + w * 512]), 16, 0, 0);          \
  }
// K frag: col-tile ct, k-slice ks -> K[ct*16+lo][ks*32 + hi*8]
#define KFRAG(buf, ct, ks)                                                              \
  (*reinterpret_cast<const bf16x8*>(                                                    \
      &Ks[buf][(ct * 16 + lo) * 64 + (((ks * 4 + hi) ^ sx) * 8)]))
// V frag: dv-tile ct, k-slice ks -> V[ct*16+lo][ks*32 + hi*8]
#define VFRAG(buf, ct, ks)                                                              \
  (*reinterpret_cast<const bf16x8*>(                                                    \
      &Vs[buf][(ct * 16 + lo) * 64 + (((ks * 4 + hi) ^ sx) * 8)]))

  float rs0 = 0.f, rs1 = 0.f, rs2 = 0.f, rs3 = 0.f;

  // ================= pass 1: row sums (32 tiles of 64 kc) =================
  u64 mc0 = mrow[0], mc1 = mrow[32], mc2 = mrow[64], mc3 = mrow[96];
  STAGE_K(0);
  asm volatile("s_waitcnt vmcnt(0)" ::: "memory");
  __builtin_amdgcn_s_barrier();
  asm volatile("" ::: "memory");

  for (int t = 0; t < 32; ++t) {
    STAGE_K(t + 1);                                   // oldest vm ops of this tile
    u64 mn0 = mrow[t + 1], mn1 = mrow[33 + t], mn2 = mrow[65 + t], mn3 = mrow[97 + t];
    asm volatile("" ::: "memory");
    const int buf = t & 1;
#pragma unroll
    for (int ct = 0; ct < 4; ++ct) {
      f32x4 s = MFMA_B16(aq1, KFRAG(buf, ct, 1), MFMA_B16(aq0, KFRAG(buf, ct, 0), fz));
      int bit = ct * 16 + lo;
      rs0 += ((mc0 >> bit) & 1ull) ? 0.f : __expf(s[0]);
      rs1 += ((mc1 >> bit) & 1ull) ? 0.f : __expf(s[1]);
      rs2 += ((mc2 >> bit) & 1ull) ? 0.f : __expf(s[2]);
      rs3 += ((mc3 >> bit) & 1ull) ? 0.f : __expf(s[3]);
    }
    mc0 = mn0; mc1 = mn1; mc2 = mn2; mc3 = mn3;
    asm volatile("s_waitcnt vmcnt(4)" ::: "memory");  // drains stage(t+1); masks(4) float
    __builtin_amdgcn_s_barrier();
    asm volatile("" ::: "memory");
  }

  {
    float v;
    v = rs0; v += __shfl_xor(v, 1); v += __shfl_xor(v, 2); v += __shfl_xor(v, 4); v += __shfl_xor(v, 8);
    rs0 = 1.f / fmaxf(v, 1e-30f);
    v = rs1; v += __shfl_xor(v, 1); v += __shfl_xor(v, 2); v += __shfl_xor(v, 4); v += __shfl_xor(v, 8);
    rs1 = 1.f / fmaxf(v, 1e-30f);
    v = rs2; v += __shfl_xor(v, 1); v += __shfl_xor(v, 2); v += __shfl_xor(v, 4); v += __shfl_xor(v, 8);
    rs2 = 1.f / fmaxf(v, 1e-30f);
    v = rs3; v += __shfl_xor(v, 1); v += __shfl_xor(v, 2); v += __shfl_xor(v, 4); v += __shfl_xor(v, 8);
    rs3 = 1.f / fmaxf(v, 1e-30f);
  }

  // ================= pass 2: normalized P -> Ps -> attn stores + PV =================
  f32x4 c0 = fz, c1 = fz, c2 = fz, c3 = fz;
  float* abase = attn + (head * NS + qr0) * NS;
  u16* psw = &Ps[w][0];
  const int srow = l >> 2, schunk = l & 3;
  const int ssx = srow & 7;                              // store-read XOR for row srow

  mc0 = mrow[0]; mc1 = mrow[32]; mc2 = mrow[64]; mc3 = mrow[96];
  STAGE_K(0);
  STAGE_V(0);
  asm volatile("s_waitcnt vmcnt(0)" ::: "memory");
  __builtin_amdgcn_s_barrier();
  asm volatile("" ::: "memory");

  for (int t = 0; t < 32; ++t) {
    STAGE_K(t + 1);                                    // oldest 4 vm ops of this tile
    STAGE_V(t + 1);
    u64 mn0 = mrow[t + 1], mn1 = mrow[33 + t], mn2 = mrow[65 + t], mn3 = mrow[97 + t];
    asm volatile("" ::: "memory");
    const int buf = t & 1;
    // QK + exp -> Ps (swizzled: chunk ^= row&7 at 8-u16 granularity)
#pragma unroll
    for (int ct = 0; ct < 4; ++ct) {
      f32x4 s = MFMA_B16(aq1, KFRAG(buf, ct, 1), MFMA_B16(aq0, KFRAG(buf, ct, 0), fz));
      int bit = ct * 16 + lo;
      int wchunk = ct * 2 + (lo >> 3), wj = lo & 7;
      float p;
      p = ((mc0 >> bit) & 1ull) ? 0.f : __expf(s[0]) * rs0;
      psw[(rbase + 0) * 64 + ((wchunk ^ ((rbase + 0) & 7)) * 8) + wj] = f2bf(p);
      p = ((mc1 >> bit) & 1ull) ? 0.f : __expf(s[1]) * rs1;
      psw[(rbase + 1) * 64 + ((wchunk ^ ((rbase + 1) & 7)) * 8) + wj] = f2bf(p);
      p = ((mc2 >> bit) & 1ull) ? 0.f : __expf(s[2]) * rs2;
      psw[(rbase + 2) * 64 + ((wchunk ^ ((rbase + 2) & 7)) * 8) + wj] = f2bf(p);
      p = ((mc3 >> bit) & 1ull) ? 0.f : __expf(s[3]) * rs3;
      psw[(rbase + 3) * 64 + ((wchunk ^ ((rbase + 3) & 7)) * 8) + wj] = f2bf(p);
    }
    mc0 = mn0; mc1 = mn1; mc2 = mn2; mc3 = mn3;
    // PV: A-frags from Ps (row=lo), B-frags from swizzled Vs
    {
      bf16x8 pa0 = *reinterpret_cast<const bf16x8*>(&psw[lo * 64 + ((hi ^ (lo & 7)) * 8)]);
      bf16x8 pa1 = *reinterpret_cast<const bf16x8*>(&psw[lo * 64 + (((4 + hi) ^ (lo & 7)) * 8)]);
      c0 = MFMA_B16(pa1, VFRAG(buf, 0, 1), MFMA_B16(pa0, VFRAG(buf, 0, 0), c0));
      c1 = MFMA_B16(pa1, VFRAG(buf, 1, 1), MFMA_B16(pa0, VFRAG(buf, 1, 0), c1));
      c2 = MFMA_B16(pa1, VFRAG(buf, 2, 1), MFMA_B16(pa0, VFRAG(buf, 2, 0), c2));
      c3 = MFMA_B16(pa1, VFRAG(buf, 3, 1), MFMA_B16(pa0, VFRAG(buf, 3, 0), c3));
    }
    // attn stores: row srow, cols schunk*16..+16 (two swizzled b128 reads -> 4 f32x4 stores)
    {
      bf16x8 q0 = *reinterpret_cast<const bf16x8*>(
          &psw[srow * 64 + (((2 * schunk) ^ ssx) * 8)]);
      bf16x8 q1 = *reinterpret_cast<const bf16x8*>(
          &psw[srow * 64 + (((2 * schunk + 1) ^ ssx) * 8)]);
      f32x4 o0, o1, o2, o3;
#pragma unroll
      for (int j = 0; j < 4; ++j) {
        o0[j] = bf2f((u16)q0[j]); o1[j] = bf2f((u16)q0[j + 4]);
        o2[j] = bf2f((u16)q1[j]); o3[j] = bf2f((u16)q1[j + 4]);
      }
      float* arow = abase + (size_t)srow * NS + t * 64 + schunk * 16;
      *reinterpret_cast<f32x4*>(arow + 0) = o0;
      *reinterpret_cast<f32x4*>(arow + 4) = o1;
      *reinterpret_cast<f32x4*>(arow + 8) = o2;
      *reinterpret_cast<f32x4*>(arow + 12) = o3;
    }
    asm volatile("s_waitcnt vmcnt(8)" ::: "memory");   // drains stages; masks4+stores4 float
    __builtin_amdgcn_s_barrier();
    asm volatile("" ::: "memory");
  }

  // ctx epilogue (P normalized -> cacc final)
#define CTXW(cv, ct)                                                                      \
  {                                                                                       \
    ctx[((size_t)b * NS + qr0 + rbase + 0) * 1024 + h * 64 + (ct)*16 + lo] = f2bf(cv[0]); \
    ctx[((size_t)b * NS + qr0 + rbase + 1) * 1024 + h * 64 + (ct)*16 + lo] = f2bf(cv[1]); \
    ctx[((size_t)b * NS + qr0 + rbase + 2) * 1024 + h * 64 + (ct)*16 + lo] = f2bf(cv[2]); \
    ctx[((size_t)b * NS + qr0 + rbase + 3) * 1024 + h * 64 + (ct)*16 + lo] = f2bf(cv[3]); \
  }
  CTXW(c0, 0) CTXW(c1, 1) CTXW(c2, 2) CTXW(c3, 3)
#undef CTXW
#undef STAGE_K
#undef STAGE_V
#undef KFRAG
#undef VFRAG
}

extern "C" void kernel_launch(void* const* d_in, const int* in_sizes, int n_in,
                              void* d_out, int out_size, void* d_ws, size_t ws_size,
                              hipStream_t stream) {
  const float* Q = (const float*)d_in[0];
  const float* K = (const float*)d_in[1];
  const float* V = (const float*)d_in[2];
  const u32* mask = (const u32*)d_in[3];
  const float* wq = (const float*)d_in[4];
  const float* bq = (const float*)d_in[5];
  const float* wk = (const float*)d_in[6];
  const float* bk = (const float*)d_in[7];
  const float* wv = (const float*)d_in[8];
  const float* bv = (const float*)d_in[9];
  const float* wo = (const float*)d_in[10];
  const float* bo = (const float*)d_in[11];
  float* out = (float*)d_out;
  float* attn = out + (size_t)NB * NS * NDM;

  char* ws = (char*)d_ws;
  u16* Qb  = (u16*)(ws + 0);
  u16* Kb  = (u16*)(ws + 8388608);
  u16* Vb  = (u16*)(ws + 16777216);
  u16* wqT = (u16*)(ws + 25165824);
  u16* wkT = (u16*)(ws + 27262976);
  u16* wvT = (u16*)(ws + 29360128);
  u16* woT = (u16*)(ws + 31457280);
  u16* qhd = (u16*)(ws + 33554432);
  u16* khd = (u16*)(ws + 41943040);
  u16* vTd = (u16*)(ws + 50331648);
  u16* ctx = (u16*)(ws + 58720256);
  u32* mbits = (u32*)(ws + 0);

  cast3_bf16<<<12288, 256, 0, stream>>>(Q, K, V, Qb, Kb, Vb);
  TW4 tw;
  tw.in[0] = wq; tw.in[1] = wk; tw.in[2] = wv; tw.in[3] = wo;
  tw.out[0] = wqT; tw.out[1] = wkT; tw.out[2] = wvT; tw.out[3] = woT;
  transpose_w4<<<dim3(32, 32, 4), 256, 0, stream>>>(tw);

  GArgs gq = {Qb, wqT, bq, (void*)qhd, 0, 0.125f};   // fold 1/sqrt(dk) into q
  GArgs gk = {Kb, wkT, bk, (void*)khd, 0, 1.0f};
  GArgs gv = {Vb, wvT, bv, (void*)vTd, 1, 1.0f};
  gemm_bt<<<dim3(32, 8, 3), 256, 0, stream>>>(gq, gk, gv);

  mask2bits<<<1024, 256, 0, stream>>>(mask, mbits);

  attn_kernel<<<1024, 256, 0, stream>>>(qhd, khd, vTd, mbits, attn, ctx);

  GArgs go = {ctx, woT, bo, d_out, 2, 1.0f};
  gemm_bt<<<dim3(32, 8, 1), 256, 0, stream>>>(go, go, go);
}

// Round 11
// 341.958 us; speedup vs baseline: 1.0626x; 1.0626x over previous
//
#include <hip/hip_runtime.h>

typedef unsigned short u16;
typedef unsigned int u32;
typedef unsigned long long u64;
typedef __attribute__((ext_vector_type(8))) short bf16x8;
typedef __attribute__((ext_vector_type(4))) float f32x4;

#define NB 2
#define NS 2048
#define NDM 1024
#define NH 16

#define MFMA_B16(a, b, c) __builtin_amdgcn_mfma_f32_16x16x32_bf16(a, b, c, 0, 0, 0)

__device__ __forceinline__ u16 f2bf(float f) {
  union { float f; unsigned u; } v; v.f = f;
  return (u16)((v.u + 0x7fffu + ((v.u >> 16) & 1u)) >> 16);
}
__device__ __forceinline__ float bf2f(u16 h) {
  union { float f; unsigned u; } v; v.u = ((u32)h) << 16; return v.f;
}

// fused cast of Q,K,V -> bf16 (3 x 1048576 float4 quads)
__global__ __launch_bounds__(256) void cast3_bf16(const float* __restrict__ a,
                                                  const float* __restrict__ b,
                                                  const float* __restrict__ c,
                                                  u16* __restrict__ oa, u16* __restrict__ ob,
                                                  u16* __restrict__ oc) {
  int i = blockIdx.x * 256 + threadIdx.x;
  const float* src; u16* dst; int j;
  if (i < 1048576) { src = a; dst = oa; j = i; }
  else if (i < 2097152) { src = b; dst = ob; j = i - 1048576; }
  else { src = c; dst = oc; j = i - 2097152; }
  const float4 v = reinterpret_cast<const float4*>(src)[j];
  ushort4 o; o.x = f2bf(v.x); o.y = f2bf(v.y); o.z = f2bf(v.z); o.w = f2bf(v.w);
  reinterpret_cast<ushort4*>(dst)[j] = o;
}

// fused transpose of the 4 weight matrices: f32 [1024][1024] -> bf16 transposed
struct TW4 { const float* in[4]; u16* out[4]; };
__global__ __launch_bounds__(256) void transpose_w4(TW4 tw) {
  __shared__ float tile[32][33];
  const float* in = tw.in[blockIdx.z];
  u16* out = tw.out[blockIdx.z];
  int bx = blockIdx.x, by = blockIdx.y;
  int x = threadIdx.x & 31, y0 = threadIdx.x >> 5;
#pragma unroll
  for (int i = 0; i < 4; i++) {
    int y = y0 + i * 8;
    tile[y][x] = in[(by * 32 + y) * NDM + bx * 32 + x];
  }
  __syncthreads();
#pragma unroll
  for (int i = 0; i < 4; i++) {
    int y = y0 + i * 8;
    out[(bx * 32 + y) * NDM + by * 32 + x] = f2bf(tile[x][y]);
  }
}

// ---- mask [B,S,S] -> bitmask, 1 bit/col ----
__global__ __launch_bounds__(256) void mask2bits(const u32* __restrict__ mask, u32* __restrict__ mb) {
  int idx = blockIdx.x * 256 + threadIdx.x;
  u32 mw0 = mask[threadIdx.x & 63];
  bool floatmode = (__ballot(mw0 == 0x3F800000u) != 0ull);
  bool bytemode = !floatmode && (__ballot((mw0 >> 8) != 0u) != 0ull);
  int row = idx >> 6;
  int wword = idx & 63;
  u32 bits = 0;
  if (!bytemode) {
    const uint4* p = reinterpret_cast<const uint4*>(mask + (size_t)row * 2048 + wword * 32);
#pragma unroll
    for (int i = 0; i < 8; i++) {
      uint4 v = p[i];
      bits |= (v.x ? 1u : 0u) << (i * 4 + 0);
      bits |= (v.y ? 1u : 0u) << (i * 4 + 1);
      bits |= (v.z ? 1u : 0u) << (i * 4 + 2);
      bits |= (v.w ? 1u : 0u) << (i * 4 + 3);
    }
  } else {
    const uint4* p = reinterpret_cast<const uint4*>(
        reinterpret_cast<const unsigned char*>(mask) + (size_t)row * 2048 + wword * 32);
#pragma unroll
    for (int i = 0; i < 2; i++) {
      uint4 v = p[i];
      u32 wsv[4] = {v.x, v.y, v.z, v.w};
#pragma unroll
      for (int j = 0; j < 4; j++)
#pragma unroll
        for (int kq = 0; kq < 4; kq++)
          bits |= ((((wsv[j] >> (kq * 8)) & 0xffu) != 0u) ? 1u : 0u) << (i * 16 + j * 4 + kq);
    }
  }
  mb[idx] = bits;
}

// ---- 128x128-tile bf16 GEMM, B^T layout ----
struct GArgs { const u16* X; const u16* W; const float* bias; void* out; int mode; float scale; };

__global__ __launch_bounds__(256, 2) void gemm_bt(GArgs g0, GArgs g1, GArgs g2) {
  GArgs ga = (blockIdx.z == 0) ? g0 : (blockIdx.z == 1 ? g1 : g2);
  const int K = 1024, N = 1024;
  __shared__ u16 As[128 * 32];
  __shared__ u16 Bs[128 * 32];
  const int t = threadIdx.x, w = t >> 6, l = t & 63;
  const int m0 = blockIdx.x * 128, n0 = blockIdx.y * 128;
  const int wm = (w >> 1) * 64, wn = (w & 1) * 64;
  const f32x4 fz = {0.f, 0.f, 0.f, 0.f};
  f32x4 acc[4][4];
#pragma unroll
  for (int i = 0; i < 4; i++)
#pragma unroll
    for (int j = 0; j < 4; j++) acc[i][j] = fz;

  for (int k0 = 0; k0 < K; k0 += 32) {
#pragma unroll
    for (int i = 0; i < 2; i++) {
      int idx = i * 256 + w * 64 + l;
      int r = idx >> 2, c = (idx & 3) * 8;
      __builtin_amdgcn_global_load_lds(
          reinterpret_cast<const unsigned*>(ga.X + (size_t)(m0 + r) * K + k0 + c),
          reinterpret_cast<unsigned*>(&As[(i * 256 + w * 64) * 8]), 16, 0, 0);
      __builtin_amdgcn_global_load_lds(
          reinterpret_cast<const unsigned*>(ga.W + (size_t)(n0 + r) * K + k0 + c),
          reinterpret_cast<unsigned*>(&Bs[(i * 256 + w * 64) * 8]), 16, 0, 0);
    }
    __syncthreads();
    bf16x8 af[4], bfr[4];
#pragma unroll
    for (int mt = 0; mt < 4; mt++)
      af[mt] = *reinterpret_cast<const bf16x8*>(&As[(wm + mt * 16 + (l & 15)) * 32 + (l >> 4) * 8]);
#pragma unroll
    for (int nt = 0; nt < 4; nt++)
      bfr[nt] = *reinterpret_cast<const bf16x8*>(&Bs[(wn + nt * 16 + (l & 15)) * 32 + (l >> 4) * 8]);
#pragma unroll
    for (int mt = 0; mt < 4; mt++)
#pragma unroll
      for (int nt = 0; nt < 4; nt++)
        acc[mt][nt] = MFMA_B16(af[mt], bfr[nt], acc[mt][nt]);
    __syncthreads();
  }

#pragma unroll
  for (int nt = 0; nt < 4; nt++) {
    int n = n0 + wn + nt * 16 + (l & 15);
    float bias = ga.bias[n];
#pragma unroll
    for (int mt = 0; mt < 4; mt++) {
      int mb = m0 + wm + mt * 16 + ((l >> 4) << 2);
#pragma unroll
      for (int r = 0; r < 4; r++) {
        int m = mb + r;
        float v = (acc[mt][nt][r] + bias) * ga.scale;
        if (ga.mode == 2) {
          reinterpret_cast<float*>(ga.out)[(size_t)m * N + n] = v;
        } else {
          int b = m >> 11, s = m & 2047, h = n >> 6, d = n & 63;
          if (ga.mode == 0)
            reinterpret_cast<u16*>(ga.out)[(((size_t)(b * NH + h) * NS + s) << 6) + d] = f2bf(v);
          else
            reinterpret_cast<u16*>(ga.out)[((size_t)(b * NH + h) * 64 + d) * NS + s] = f2bf(v);
        }
      }
    }
  }
}

// ---- attention: R9 structure at half-block granularity.
// 2048 blocks x 128 threads (2 waves x 16 q-rows), KVBLK=32, K+V LDS double-buffered
// (XOR-swizzled both sides), masks register-prefetched 1 tile ahead, counted vmcnt.
// LDS = 8K(K)+8K(V)+2.5K(Ps) = 18944 B -> 8 blocks/CU, 8 independent barrier groups. ----
__global__ __launch_bounds__(128, 4) void attn_kernel(
    const u16* __restrict__ qh, const u16* __restrict__ kh, const u16* __restrict__ vT,
    const u32* __restrict__ mb, float* __restrict__ attn, u16* __restrict__ ctx) {
  __shared__ u16 Ks[2][32 * 64];
  __shared__ u16 Vs[2][64 * 32];
  __shared__ u16 Ps[2][16 * 40];
  const int tid = threadIdx.x, w = tid >> 6, l = tid & 63;
  int id = blockIdx.x;
  int wgid = (id & 7) * 256 + (id >> 3);   // XCD-chunked bijective swizzle (2048 % 8 == 0)
  int qt = wgid & 63, pr = wgid >> 6;      // 64 q-subtiles of 32 rows per (b,h)
  int h = pr & 15, b = pr >> 4;
  const size_t head = (size_t)b * NH + h;
  const u16* qp = qh + head * NS * 64;
  const u16* kp = kh + head * NS * 64;
  const u16* vp = vT + head * 64 * NS;
  const int qr0 = qt * 32 + w * 16;        // per-wave 16-row base
  const int lo = l & 15, hi = l >> 4;
  const int rbase = hi << 2;
  const f32x4 fz = {0.f, 0.f, 0.f, 0.f};

  bf16x8 aq0, aq1;
  {
    const u16* p = qp + (size_t)(qr0 + lo) * 64 + hi * 8;
    aq0 = *reinterpret_cast<const bf16x8*>(p);
    aq1 = *reinterpret_cast<const bf16x8*>(p + 32);
  }
  const u32* mrow = mb + ((size_t)b * NS + qr0 + rbase) * 64;  // 64 u32 words per row

  // staging sources (128 threads -> 2 ops per 4KB tile), pre-swizzled (rule #21)
  const int k_row = tid >> 3, k_slot = tid & 7;          // rows 0..15 (op0), +16 (op1)
  const u16* ksrcA = kp + (size_t)k_row * 64 + ((k_slot ^ (k_row & 7)) * 8);
  const u16* ksrcB = ksrcA + 16 * 64;                    // (row+16)&7 == row&7 -> same swizzle
  const int v_dv = tid >> 2, v_slot = tid & 3;           // dv 0..31 (op0), +32 (op1)
  const u16* vsrcA = vp + (size_t)v_dv * NS + ((v_slot ^ ((v_dv >> 1) & 3)) * 8);
  const u16* vsrcB = vsrcA + (size_t)32 * NS;            // ((dv+32)>>1)&3 == (dv>>1)&3
  const int sxk = lo & 7;
  const int sxv = (lo >> 1) & 3;

#define STAGE_KT(tt)                                                                    \
  {                                                                                     \
    __builtin_amdgcn_global_load_lds(                                                   \
        reinterpret_cast<const unsigned*>(ksrcA + (size_t)(tt) * 2048),                 \
        reinterpret_cast<unsigned*>(&Ks[(tt) & 1][w * 512]), 16, 0, 0);                 \
    __builtin_amdgcn_global_load_lds(                                                   \
        reinterpret_cast<const unsigned*>(ksrcB + (size_t)(tt) * 2048),                 \
        reinterpret_cast<unsigned*>(&Ks[(tt) & 1][1024 + w * 512]), 16, 0, 0);          \
  }
#define STAGE_VT(tt)                                                                    \
  {                                                                                     \
    __builtin_amdgcn_global_load_lds(                                                   \
        reinterpret_cast<const unsigned*>(vsrcA + (size_t)(tt) * 32),                   \
        reinterpret_cast<unsigned*>(&Vs[(tt) & 1][w * 512]), 16, 0, 0);                 \
    __builtin_amdgcn_global_load_lds(                                                   \
        reinterpret_cast<const unsigned*>(vsrcB + (size_t)(tt) * 32),                   \
        reinterpret_cast<unsigned*>(&Vs[(tt) & 1][1024 + w * 512]), 16, 0, 0);          \
  }

  float rs0 = 0.f, rs1 = 0.f, rs2 = 0.f, rs3 = 0.f;

  // ================= pass 1: row sums =================
  u32 mc0 = mrow[0], mc1 = mrow[64], mc2 = mrow[128], mc3 = mrow[192];
  STAGE_KT(0);
  asm volatile("s_waitcnt vmcnt(0)" ::: "memory");
  __builtin_amdgcn_s_barrier();
  asm volatile("" ::: "memory");

  for (int t = 0; t < 64; ++t) {
    STAGE_KT(t + 1);                                   // oldest vm ops of this tile
    u32 mn0 = mrow[t + 1], mn1 = mrow[65 + t], mn2 = mrow[129 + t], mn3 = mrow[193 + t];
    asm volatile("" ::: "memory");
    const u16* kbase = &Ks[t & 1][0];
    bf16x8 b00 = *reinterpret_cast<const bf16x8*>(&kbase[(lo) * 64 + ((hi ^ sxk) * 8)]);
    bf16x8 b01 = *reinterpret_cast<const bf16x8*>(&kbase[(lo) * 64 + (((4 + hi) ^ sxk) * 8)]);
    bf16x8 b10 = *reinterpret_cast<const bf16x8*>(&kbase[(16 + lo) * 64 + ((hi ^ sxk) * 8)]);
    bf16x8 b11 = *reinterpret_cast<const bf16x8*>(&kbase[(16 + lo) * 64 + (((4 + hi) ^ sxk) * 8)]);
    f32x4 s0 = MFMA_B16(aq1, b01, MFMA_B16(aq0, b00, fz));
    f32x4 s1 = MFMA_B16(aq1, b11, MFMA_B16(aq0, b10, fz));
    rs0 += ((mc0 >> lo) & 1u) ? 0.f : __expf(s0[0]);
    rs1 += ((mc1 >> lo) & 1u) ? 0.f : __expf(s0[1]);
    rs2 += ((mc2 >> lo) & 1u) ? 0.f : __expf(s0[2]);
    rs3 += ((mc3 >> lo) & 1u) ? 0.f : __expf(s0[3]);
    int bit1 = 16 + lo;
    rs0 += ((mc0 >> bit1) & 1u) ? 0.f : __expf(s1[0]);
    rs1 += ((mc1 >> bit1) & 1u) ? 0.f : __expf(s1[1]);
    rs2 += ((mc2 >> bit1) & 1u) ? 0.f : __expf(s1[2]);
    rs3 += ((mc3 >> bit1) & 1u) ? 0.f : __expf(s1[3]);
    mc0 = mn0; mc1 = mn1; mc2 = mn2; mc3 = mn3;
    asm volatile("s_waitcnt vmcnt(4)" ::: "memory");   // drains stage(t+1); mask(t+1) floats
    __builtin_amdgcn_s_barrier();
    asm volatile("" ::: "memory");
  }

  {
    float v;
    v = rs0; v += __shfl_xor(v, 1); v += __shfl_xor(v, 2); v += __shfl_xor(v, 4); v += __shfl_xor(v, 8);
    rs0 = 1.f / fmaxf(v, 1e-30f);
    v = rs1; v += __shfl_xor(v, 1); v += __shfl_xor(v, 2); v += __shfl_xor(v, 4); v += __shfl_xor(v, 8);
    rs1 = 1.f / fmaxf(v, 1e-30f);
    v = rs2; v += __shfl_xor(v, 1); v += __shfl_xor(v, 2); v += __shfl_xor(v, 4); v += __shfl_xor(v, 8);
    rs2 = 1.f / fmaxf(v, 1e-30f);
    v = rs3; v += __shfl_xor(v, 1); v += __shfl_xor(v, 2); v += __shfl_xor(v, 4); v += __shfl_xor(v, 8);
    rs3 = 1.f / fmaxf(v, 1e-30f);
  }

  // ================= pass 2: normalized P -> Ps -> attn stores + PV =================
  f32x4 c0 = fz, c1 = fz, c2 = fz, c3 = fz;
  float* abase = attn + (head * NS + qr0) * NS;
  u16* psw = &Ps[w][0];
  const int srow = l >> 2, schunk = l & 3;

  mc0 = mrow[0]; mc1 = mrow[64]; mc2 = mrow[128]; mc3 = mrow[192];
  STAGE_KT(0);
  STAGE_VT(0);
  asm volatile("s_waitcnt vmcnt(0)" ::: "memory");
  __builtin_amdgcn_s_barrier();
  asm volatile("" ::: "memory");

  for (int t = 0; t < 64; ++t) {
    STAGE_KT(t + 1);                                   // oldest 4 vm ops of this tile
    STAGE_VT(t + 1);
    u32 mn0 = mrow[t + 1], mn1 = mrow[65 + t], mn2 = mrow[129 + t], mn3 = mrow[193 + t];
    asm volatile("" ::: "memory");
    const u16* kbase = &Ks[t & 1][0];
    const u16* vbase = &Vs[t & 1][0];
    bf16x8 b00 = *reinterpret_cast<const bf16x8*>(&kbase[(lo) * 64 + ((hi ^ sxk) * 8)]);
    bf16x8 b01 = *reinterpret_cast<const bf16x8*>(&kbase[(lo) * 64 + (((4 + hi) ^ sxk) * 8)]);
    bf16x8 b10 = *reinterpret_cast<const bf16x8*>(&kbase[(16 + lo) * 64 + ((hi ^ sxk) * 8)]);
    bf16x8 b11 = *reinterpret_cast<const bf16x8*>(&kbase[(16 + lo) * 64 + (((4 + hi) ^ sxk) * 8)]);
    f32x4 s0 = MFMA_B16(aq1, b01, MFMA_B16(aq0, b00, fz));
    f32x4 s1 = MFMA_B16(aq1, b11, MFMA_B16(aq0, b10, fz));
    float p;
    p = ((mc0 >> lo) & 1u) ? 0.f : __expf(s0[0]) * rs0; psw[(rbase + 0) * 40 + lo] = f2bf(p);
    p = ((mc1 >> lo) & 1u) ? 0.f : __expf(s0[1]) * rs1; psw[(rbase + 1) * 40 + lo] = f2bf(p);
    p = ((mc2 >> lo) & 1u) ? 0.f : __expf(s0[2]) * rs2; psw[(rbase + 2) * 40 + lo] = f2bf(p);
    p = ((mc3 >> lo) & 1u) ? 0.f : __expf(s0[3]) * rs3; psw[(rbase + 3) * 40 + lo] = f2bf(p);
    int bit1 = 16 + lo;
    p = ((mc0 >> bit1) & 1u) ? 0.f : __expf(s1[0]) * rs0; psw[(rbase + 0) * 40 + 16 + lo] = f2bf(p);
    p = ((mc1 >> bit1) & 1u) ? 0.f : __expf(s1[1]) * rs1; psw[(rbase + 1) * 40 + 16 + lo] = f2bf(p);
    p = ((mc2 >> bit1) & 1u) ? 0.f : __expf(s1[2]) * rs2; psw[(rbase + 2) * 40 + 16 + lo] = f2bf(p);
    p = ((mc3 >> bit1) & 1u) ? 0.f : __expf(s1[3]) * rs3; psw[(rbase + 3) * 40 + 16 + lo] = f2bf(p);
    mc0 = mn0; mc1 = mn1; mc2 = mn2; mc3 = mn3;
    // PV: A-frag from Ps, B-frags from swizzled Vs
    {
      bf16x8 pa = *reinterpret_cast<const bf16x8*>(&psw[lo * 40 + hi * 8]);
      bf16x8 v0 = *reinterpret_cast<const bf16x8*>(&vbase[(lo) * 32 + ((hi ^ sxv) * 8)]);
      bf16x8 v1 = *reinterpret_cast<const bf16x8*>(&vbase[(16 + lo) * 32 + ((hi ^ sxv) * 8)]);
      bf16x8 v2 = *reinterpret_cast<const bf16x8*>(&vbase[(32 + lo) * 32 + ((hi ^ sxv) * 8)]);
      bf16x8 v3 = *reinterpret_cast<const bf16x8*>(&vbase[(48 + lo) * 32 + ((hi ^ sxv) * 8)]);
      c0 = MFMA_B16(pa, v0, c0);
      c1 = MFMA_B16(pa, v1, c1);
      c2 = MFMA_B16(pa, v2, c2);
      c3 = MFMA_B16(pa, v3, c3);
    }
    // attn stores from Ps: per wave 16 rows x 32 cols (bf16<<16 -> f32), 32B per lane
    {
      float* arow = abase + (size_t)srow * NS + t * 32 + schunk * 8;
      bf16x8 q0 = *reinterpret_cast<const bf16x8*>(&psw[srow * 40 + schunk * 8]);
      f32x4 o0, o1;
#pragma unroll
      for (int j = 0; j < 4; ++j) { o0[j] = bf2f((u16)q0[j]); o1[j] = bf2f((u16)q0[j + 4]); }
      *reinterpret_cast<f32x4*>(arow + 0) = o0;
      *reinterpret_cast<f32x4*>(arow + 4) = o1;
    }
    asm volatile("s_waitcnt vmcnt(6)" ::: "memory");   // drains stages(4); mask4+stores2 float
    __builtin_amdgcn_s_barrier();
    asm volatile("" ::: "memory");
  }

  // ctx epilogue (P normalized -> cacc final)
#define CTXW(cv, ct)                                                                      \
  {                                                                                       \
    ctx[((size_t)b * NS + qr0 + rbase + 0) * 1024 + h * 64 + (ct)*16 + lo] = f2bf(cv[0]); \
    ctx[((size_t)b * NS + qr0 + rbase + 1) * 1024 + h * 64 + (ct)*16 + lo] = f2bf(cv[1]); \
    ctx[((size_t)b * NS + qr0 + rbase + 2) * 1024 + h * 64 + (ct)*16 + lo] = f2bf(cv[2]); \
    ctx[((size_t)b * NS + qr0 + rbase + 3) * 1024 + h * 64 + (ct)*16 + lo] = f2bf(cv[3]); \
  }
  CTXW(c0, 0) CTXW(c1, 1) CTXW(c2, 2) CTXW(c3, 3)
#undef CTXW
#undef STAGE_KT
#undef STAGE_VT
}

extern "C" void kernel_launch(void* const* d_in, const int* in_sizes, int n_in,
                              void* d_out, int out_size, void* d_ws, size_t ws_size,
                              hipStream_t stream) {
  const float* Q = (const float*)d_in[0];
  const float* K = (const float*)d_in[1];
  const float* V = (const float*)d_in[2];
  const u32* mask = (const u32*)d_in[3];
  const float* wq = (const float*)d_in[4];
  const float* bq = (const float*)d_in[5];
  const float* wk = (const float*)d_in[6];
  const float* bk = (const float*)d_in[7];
  const float* wv = (const float*)d_in[8];
  const float* bv = (const float*)d_in[9];
  const float* wo = (const float*)d_in[10];
  const float* bo = (const float*)d_in[11];
  float* out = (float*)d_out;
  float* attn = out + (size_t)NB * NS * NDM;

  char* ws = (char*)d_ws;
  u16* Qb  = (u16*)(ws + 0);
  u16* Kb  = (u16*)(ws + 8388608);
  u16* Vb  = (u16*)(ws + 16777216);
  u16* wqT = (u16*)(ws + 25165824);
  u16* wkT = (u16*)(ws + 27262976);
  u16* wvT = (u16*)(ws + 29360128);
  u16* woT = (u16*)(ws + 31457280);
  u16* qhd = (u16*)(ws + 33554432);
  u16* khd = (u16*)(ws + 41943040);
  u16* vTd = (u16*)(ws + 50331648);
  u16* ctx = (u16*)(ws + 58720256);
  u32* mbits = (u32*)(ws + 0);

  cast3_bf16<<<12288, 256, 0, stream>>>(Q, K, V, Qb, Kb, Vb);
  TW4 tw;
  tw.in[0] = wq; tw.in[1] = wk; tw.in[2] = wv; tw.in[3] = wo;
  tw.out[0] = wqT; tw.out[1] = wkT; tw.out[2] = wvT; tw.out[3] = woT;
  transpose_w4<<<dim3(32, 32, 4), 256, 0, stream>>>(tw);

  GArgs gq = {Qb, wqT, bq, (void*)qhd, 0, 0.125f};   // fold 1/sqrt(dk) into q
  GArgs gk = {Kb, wkT, bk, (void*)khd, 0, 1.0f};
  GArgs gv = {Vb, wvT, bv, (void*)vTd, 1, 1.0f};
  gemm_bt<<<dim3(32, 8, 3), 256, 0, stream>>>(gq, gk, gv);

  mask2bits<<<1024, 256, 0, stream>>>(mask, mbits);

  attn_kernel<<<2048, 128, 0, stream>>>(qhd, khd, vTd, mbits, attn, ctx);

  GArgs go = {ctx, woT, bo, d_out, 2, 1.0f};
  gemm_bt<<<dim3(32, 8, 1), 256, 0, stream>>>(go, go, go);
}

// Round 12
// 338.935 us; speedup vs baseline: 1.0720x; 1.0089x over previous
//
#include <hip/hip_runtime.h>

typedef unsigned short u16;
typedef unsigned int u32;
typedef unsigned long long u64;
typedef __attribute__((ext_vector_type(8))) short bf16x8;
typedef __attribute__((ext_vector_type(4))) float f32x4;

#define NB 2
#define NS 2048
#define NDM 1024
#define NH 16

#define MFMA_B16(a, b, c) __builtin_amdgcn_mfma_f32_16x16x32_bf16(a, b, c, 0, 0, 0)

__device__ __forceinline__ u16 f2bf(float f) {
  union { float f; unsigned u; } v; v.f = f;
  return (u16)((v.u + 0x7fffu + ((v.u >> 16) & 1u)) >> 16);
}
__device__ __forceinline__ float bf2f(u16 h) {
  union { float f; unsigned u; } v; v.u = ((u32)h) << 16; return v.f;
}

// fused cast of Q,K,V -> bf16 (3 x 1048576 float4 quads)
__global__ __launch_bounds__(256) void cast3_bf16(const float* __restrict__ a,
                                                  const float* __restrict__ b,
                                                  const float* __restrict__ c,
                                                  u16* __restrict__ oa, u16* __restrict__ ob,
                                                  u16* __restrict__ oc) {
  int i = blockIdx.x * 256 + threadIdx.x;
  const float* src; u16* dst; int j;
  if (i < 1048576) { src = a; dst = oa; j = i; }
  else if (i < 2097152) { src = b; dst = ob; j = i - 1048576; }
  else { src = c; dst = oc; j = i - 2097152; }
  const float4 v = reinterpret_cast<const float4*>(src)[j];
  ushort4 o; o.x = f2bf(v.x); o.y = f2bf(v.y); o.z = f2bf(v.z); o.w = f2bf(v.w);
  reinterpret_cast<ushort4*>(dst)[j] = o;
}

// fused transpose of the 4 weight matrices: f32 [1024][1024] -> bf16 transposed
struct TW4 { const float* in[4]; u16* out[4]; };
__global__ __launch_bounds__(256) void transpose_w4(TW4 tw) {
  __shared__ float tile[32][33];
  const float* in = tw.in[blockIdx.z];
  u16* out = tw.out[blockIdx.z];
  int bx = blockIdx.x, by = blockIdx.y;
  int x = threadIdx.x & 31, y0 = threadIdx.x >> 5;
#pragma unroll
  for (int i = 0; i < 4; i++) {
    int y = y0 + i * 8;
    tile[y][x] = in[(by * 32 + y) * NDM + bx * 32 + x];
  }
  __syncthreads();
#pragma unroll
  for (int i = 0; i < 4; i++) {
    int y = y0 + i * 8;
    out[(bx * 32 + y) * NDM + by * 32 + x] = f2bf(tile[x][y]);
  }
}

// ---- mask [B,S,S] -> bitmask, 1 bit/col ----
__global__ __launch_bounds__(256) void mask2bits(const u32* __restrict__ mask, u32* __restrict__ mb) {
  int idx = blockIdx.x * 256 + threadIdx.x;
  u32 mw0 = mask[threadIdx.x & 63];
  bool floatmode = (__ballot(mw0 == 0x3F800000u) != 0ull);
  bool bytemode = !floatmode && (__ballot((mw0 >> 8) != 0u) != 0ull);
  int row = idx >> 6;
  int wword = idx & 63;
  u32 bits = 0;
  if (!bytemode) {
    const uint4* p = reinterpret_cast<const uint4*>(mask + (size_t)row * 2048 + wword * 32);
#pragma unroll
    for (int i = 0; i < 8; i++) {
      uint4 v = p[i];
      bits |= (v.x ? 1u : 0u) << (i * 4 + 0);
      bits |= (v.y ? 1u : 0u) << (i * 4 + 1);
      bits |= (v.z ? 1u : 0u) << (i * 4 + 2);
      bits |= (v.w ? 1u : 0u) << (i * 4 + 3);
    }
  } else {
    const uint4* p = reinterpret_cast<const uint4*>(
        reinterpret_cast<const unsigned char*>(mask) + (size_t)row * 2048 + wword * 32);
#pragma unroll
    for (int i = 0; i < 2; i++) {
      uint4 v = p[i];
      u32 wsv[4] = {v.x, v.y, v.z, v.w};
#pragma unroll
      for (int j = 0; j < 4; j++)
#pragma unroll
        for (int kq = 0; kq < 4; kq++)
          bits |= ((((wsv[j] >> (kq * 8)) & 0xffu) != 0u) ? 1u : 0u) << (i * 16 + j * 4 + kq);
    }
  }
  mb[idx] = bits;
}

// ---- 128x128-tile bf16 GEMM, B^T layout ----
struct GArgs { const u16* X; const u16* W; const float* bias; void* out; int mode; float scale; };

__global__ __launch_bounds__(256, 2) void gemm_bt(GArgs g0, GArgs g1, GArgs g2) {
  GArgs ga = (blockIdx.z == 0) ? g0 : (blockIdx.z == 1 ? g1 : g2);
  const int K = 1024, N = 1024;
  __shared__ u16 As[128 * 32];
  __shared__ u16 Bs[128 * 32];
  const int t = threadIdx.x, w = t >> 6, l = t & 63;
  const int m0 = blockIdx.x * 128, n0 = blockIdx.y * 128;
  const int wm = (w >> 1) * 64, wn = (w & 1) * 64;
  const f32x4 fz = {0.f, 0.f, 0.f, 0.f};
  f32x4 acc[4][4];
#pragma unroll
  for (int i = 0; i < 4; i++)
#pragma unroll
    for (int j = 0; j < 4; j++) acc[i][j] = fz;

  for (int k0 = 0; k0 < K; k0 += 32) {
#pragma unroll
    for (int i = 0; i < 2; i++) {
      int idx = i * 256 + w * 64 + l;
      int r = idx >> 2, c = (idx & 3) * 8;
      __builtin_amdgcn_global_load_lds(
          reinterpret_cast<const unsigned*>(ga.X + (size_t)(m0 + r) * K + k0 + c),
          reinterpret_cast<unsigned*>(&As[(i * 256 + w * 64) * 8]), 16, 0, 0);
      __builtin_amdgcn_global_load_lds(
          reinterpret_cast<const unsigned*>(ga.W + (size_t)(n0 + r) * K + k0 + c),
          reinterpret_cast<unsigned*>(&Bs[(i * 256 + w * 64) * 8]), 16, 0, 0);
    }
    __syncthreads();
    bf16x8 af[4], bfr[4];
#pragma unroll
    for (int mt = 0; mt < 4; mt++)
      af[mt] = *reinterpret_cast<const bf16x8*>(&As[(wm + mt * 16 + (l & 15)) * 32 + (l >> 4) * 8]);
#pragma unroll
    for (int nt = 0; nt < 4; nt++)
      bfr[nt] = *reinterpret_cast<const bf16x8*>(&Bs[(wn + nt * 16 + (l & 15)) * 32 + (l >> 4) * 8]);
#pragma unroll
    for (int mt = 0; mt < 4; mt++)
#pragma unroll
      for (int nt = 0; nt < 4; nt++)
        acc[mt][nt] = MFMA_B16(af[mt], bfr[nt], acc[mt][nt]);
    __syncthreads();
  }

#pragma unroll
  for (int nt = 0; nt < 4; nt++) {
    int n = n0 + wn + nt * 16 + (l & 15);
    float bias = ga.bias[n];
#pragma unroll
    for (int mt = 0; mt < 4; mt++) {
      int mb = m0 + wm + mt * 16 + ((l >> 4) << 2);
#pragma unroll
      for (int r = 0; r < 4; r++) {
        int m = mb + r;
        float v = (acc[mt][nt][r] + bias) * ga.scale;
        if (ga.mode == 2) {
          reinterpret_cast<float*>(ga.out)[(size_t)m * N + n] = v;
        } else {
          int b = m >> 11, s = m & 2047, h = n >> 6, d = n & 63;
          if (ga.mode == 0)
            reinterpret_cast<u16*>(ga.out)[(((size_t)(b * NH + h) * NS + s) << 6) + d] = f2bf(v);
          else
            reinterpret_cast<u16*>(ga.out)[((size_t)(b * NH + h) * 64 + d) * NS + s] = f2bf(v);
        }
      }
    }
  }
}

// ---- attention: R9 structure + 2-AHEAD staging (triple-buffered K/V rings).
// KVBLK=32, masks prefetched 2 tiles ahead. Per-tile issue order:
// stage(t+2) -> mask(t+2) -> compute -> stores. Barrier waits: pass1 vmcnt(6),
// pass2 vmcnt(10) -- drains stage(t+1), keeps stage(t+2) in flight.
// LDS = 3*4K(K) + 3*4K(V) + 5K(Ps) = 29696 B -> 4 blocks/CU. ----
__global__ __launch_bounds__(256, 4) void attn_kernel(
    const u16* __restrict__ qh, const u16* __restrict__ kh, const u16* __restrict__ vT,
    const u32* __restrict__ mb, float* __restrict__ attn, u16* __restrict__ ctx) {
  __shared__ u16 Ks[3][32 * 64];
  __shared__ u16 Vs[3][64 * 32];
  __shared__ u16 Ps[4][16 * 40];
  const int tid = threadIdx.x, w = tid >> 6, l = tid & 63;
  int id = blockIdx.x;
  int wgid = (id & 7) * 128 + (id >> 3);   // XCD-chunked bijective swizzle (1024 % 8 == 0)
  int qt = wgid & 31, pr = wgid >> 5;
  int h = pr & 15, b = pr >> 4;
  const size_t head = (size_t)b * NH + h;
  const u16* qp = qh + head * NS * 64;
  const u16* kp = kh + head * NS * 64;
  const u16* vp = vT + head * 64 * NS;
  const int qr0 = qt * 64 + w * 16;
  const int lo = l & 15, hi = l >> 4;
  const int rbase = hi << 2;
  const f32x4 fz = {0.f, 0.f, 0.f, 0.f};

  bf16x8 aq0, aq1;
  {
    const u16* p = qp + (size_t)(qr0 + lo) * 64 + hi * 8;
    aq0 = *reinterpret_cast<const bf16x8*>(p);
    aq1 = *reinterpret_cast<const bf16x8*>(p + 32);
  }
  const u32* mrow = mb + ((size_t)b * NS + qr0 + rbase) * 64;  // 64 u32 words per row

  // staging sources, pre-swizzled (involution: same XOR applied on ds_read)
  const int k_row = tid >> 3, k_slot = tid & 7;
  const u16* ksrc0 = kp + (size_t)k_row * 64 + ((k_slot ^ (k_row & 7)) * 8);
  const int v_dv = tid >> 2, v_slot = tid & 3;
  const u16* vsrc0 = vp + (size_t)v_dv * NS + ((v_slot ^ ((v_dv >> 1) & 3)) * 8);
  const int sxk = lo & 7;
  const int sxv = (lo >> 1) & 3;

#define STAGE_KT(tt, bi)                                                                \
  __builtin_amdgcn_global_load_lds(                                                     \
      reinterpret_cast<const unsigned*>(ksrc0 + (size_t)(tt) * 2048),                   \
      reinterpret_cast<unsigned*>(&Ks[bi][w * 512]), 16, 0, 0);
#define STAGE_VT(tt, bi)                                                                \
  __builtin_amdgcn_global_load_lds(                                                     \
      reinterpret_cast<const unsigned*>(vsrc0 + (size_t)(tt) * 32),                     \
      reinterpret_cast<unsigned*>(&Vs[bi][w * 512]), 16, 0, 0);

  float rs0 = 0.f, rs1 = 0.f, rs2 = 0.f, rs3 = 0.f;

  // ================= pass 1: row sums =================
  u32 mc0 = mrow[0], mc1 = mrow[64], mc2 = mrow[128], mc3 = mrow[192];
  u32 mn0 = mrow[1], mn1 = mrow[65], mn2_ = mrow[129], mn3 = mrow[193];
  STAGE_KT(0, 0);
  STAGE_KT(1, 1);
  asm volatile("s_waitcnt vmcnt(2)" ::: "memory");  // masks+st0 done; st1 in flight
  __builtin_amdgcn_s_barrier();
  asm volatile("" ::: "memory");

  {
    int cur = 0;
    for (int t = 0; t < 64; ++t) {
      int nxt2 = cur + 2; if (nxt2 >= 3) nxt2 -= 3;
      if (t + 2 < 64) STAGE_KT(t + 2, nxt2);
      u32 f0 = mrow[t + 2], f1 = mrow[66 + t], f2 = mrow[130 + t], f3 = mrow[194 + t];
      asm volatile("" ::: "memory");
      const u16* kbase = &Ks[cur][0];
      bf16x8 b00 = *reinterpret_cast<const bf16x8*>(&kbase[(lo) * 64 + ((hi ^ sxk) * 8)]);
      bf16x8 b01 = *reinterpret_cast<const bf16x8*>(&kbase[(lo) * 64 + (((4 + hi) ^ sxk) * 8)]);
      bf16x8 b10 = *reinterpret_cast<const bf16x8*>(&kbase[(16 + lo) * 64 + ((hi ^ sxk) * 8)]);
      bf16x8 b11 = *reinterpret_cast<const bf16x8*>(&kbase[(16 + lo) * 64 + (((4 + hi) ^ sxk) * 8)]);
      f32x4 s0 = MFMA_B16(aq1, b01, MFMA_B16(aq0, b00, fz));
      f32x4 s1 = MFMA_B16(aq1, b11, MFMA_B16(aq0, b10, fz));
      rs0 += ((mc0 >> lo) & 1u) ? 0.f : __expf(s0[0]);
      rs1 += ((mc1 >> lo) & 1u) ? 0.f : __expf(s0[1]);
      rs2 += ((mc2 >> lo) & 1u) ? 0.f : __expf(s0[2]);
      rs3 += ((mc3 >> lo) & 1u) ? 0.f : __expf(s0[3]);
      int bit1 = 16 + lo;
      rs0 += ((mc0 >> bit1) & 1u) ? 0.f : __expf(s1[0]);
      rs1 += ((mc1 >> bit1) & 1u) ? 0.f : __expf(s1[1]);
      rs2 += ((mc2 >> bit1) & 1u) ? 0.f : __expf(s1[2]);
      rs3 += ((mc3 >> bit1) & 1u) ? 0.f : __expf(s1[3]);
      mc0 = mn0; mc1 = mn1; mc2 = mn2_; mc3 = mn3;
      mn0 = f0; mn1 = f1; mn2_ = f2; mn3 = f3;
      asm volatile("s_waitcnt vmcnt(6)" ::: "memory");  // st(t+1) done; st(t+2)+mask in flight
      __builtin_amdgcn_s_barrier();
      asm volatile("" ::: "memory");
      cur = (cur + 1 == 3) ? 0 : cur + 1;
    }
  }

  {
    float v;
    v = rs0; v += __shfl_xor(v, 1); v += __shfl_xor(v, 2); v += __shfl_xor(v, 4); v += __shfl_xor(v, 8);
    rs0 = 1.f / fmaxf(v, 1e-30f);
    v = rs1; v += __shfl_xor(v, 1); v += __shfl_xor(v, 2); v += __shfl_xor(v, 4); v += __shfl_xor(v, 8);
    rs1 = 1.f / fmaxf(v, 1e-30f);
    v = rs2; v += __shfl_xor(v, 1); v += __shfl_xor(v, 2); v += __shfl_xor(v, 4); v += __shfl_xor(v, 8);
    rs2 = 1.f / fmaxf(v, 1e-30f);
    v = rs3; v += __shfl_xor(v, 1); v += __shfl_xor(v, 2); v += __shfl_xor(v, 4); v += __shfl_xor(v, 8);
    rs3 = 1.f / fmaxf(v, 1e-30f);
  }

  // ================= pass 2: normalized P -> Ps -> attn stores + PV =================
  f32x4 c0 = fz, c1 = fz, c2 = fz, c3 = fz;
  float* abase = attn + (head * NS + qr0) * NS;
  u16* psw = &Ps[w][0];
  const int srow = l >> 2, schunk = l & 3;

  mc0 = mrow[0]; mc1 = mrow[64]; mc2 = mrow[128]; mc3 = mrow[192];
  u32 mo0 = mrow[1], mo1 = mrow[65], mo2 = mrow[129], mo3 = mrow[193];
  STAGE_KT(0, 0);
  STAGE_VT(0, 0);
  STAGE_KT(1, 1);
  STAGE_VT(1, 1);
  asm volatile("s_waitcnt vmcnt(4)" ::: "memory");  // masks+st0 done; st1 in flight
  __builtin_amdgcn_s_barrier();
  asm volatile("" ::: "memory");

  {
    int cur = 0;
    for (int t = 0; t < 64; ++t) {
      int nxt2 = cur + 2; if (nxt2 >= 3) nxt2 -= 3;
      if (t + 2 < 64) { STAGE_KT(t + 2, nxt2); STAGE_VT(t + 2, nxt2); }
      u32 f0 = mrow[t + 2], f1 = mrow[66 + t], f2 = mrow[130 + t], f3 = mrow[194 + t];
      asm volatile("" ::: "memory");
      const u16* kbase = &Ks[cur][0];
      const u16* vbase = &Vs[cur][0];
      bf16x8 b00 = *reinterpret_cast<const bf16x8*>(&kbase[(lo) * 64 + ((hi ^ sxk) * 8)]);
      bf16x8 b01 = *reinterpret_cast<const bf16x8*>(&kbase[(lo) * 64 + (((4 + hi) ^ sxk) * 8)]);
      bf16x8 b10 = *reinterpret_cast<const bf16x8*>(&kbase[(16 + lo) * 64 + ((hi ^ sxk) * 8)]);
      bf16x8 b11 = *reinterpret_cast<const bf16x8*>(&kbase[(16 + lo) * 64 + (((4 + hi) ^ sxk) * 8)]);
      f32x4 s0 = MFMA_B16(aq1, b01, MFMA_B16(aq0, b00, fz));
      f32x4 s1 = MFMA_B16(aq1, b11, MFMA_B16(aq0, b10, fz));
      float p;
      p = ((mc0 >> lo) & 1u) ? 0.f : __expf(s0[0]) * rs0; psw[(rbase + 0) * 40 + lo] = f2bf(p);
      p = ((mc1 >> lo) & 1u) ? 0.f : __expf(s0[1]) * rs1; psw[(rbase + 1) * 40 + lo] = f2bf(p);
      p = ((mc2 >> lo) & 1u) ? 0.f : __expf(s0[2]) * rs2; psw[(rbase + 2) * 40 + lo] = f2bf(p);
      p = ((mc3 >> lo) & 1u) ? 0.f : __expf(s0[3]) * rs3; psw[(rbase + 3) * 40 + lo] = f2bf(p);
      int bit1 = 16 + lo;
      p = ((mc0 >> bit1) & 1u) ? 0.f : __expf(s1[0]) * rs0; psw[(rbase + 0) * 40 + 16 + lo] = f2bf(p);
      p = ((mc1 >> bit1) & 1u) ? 0.f : __expf(s1[1]) * rs1; psw[(rbase + 1) * 40 + 16 + lo] = f2bf(p);
      p = ((mc2 >> bit1) & 1u) ? 0.f : __expf(s1[2]) * rs2; psw[(rbase + 2) * 40 + 16 + lo] = f2bf(p);
      p = ((mc3 >> bit1) & 1u) ? 0.f : __expf(s1[3]) * rs3; psw[(rbase + 3) * 40 + 16 + lo] = f2bf(p);
      mc0 = mo0; mc1 = mo1; mc2 = mo2; mc3 = mo3;
      mo0 = f0; mo1 = f1; mo2 = f2; mo3 = f3;
      // PV: A-frag from Ps, B-frags from swizzled Vs
      {
        bf16x8 pa = *reinterpret_cast<const bf16x8*>(&psw[lo * 40 + hi * 8]);
        bf16x8 v0 = *reinterpret_cast<const bf16x8*>(&vbase[(lo) * 32 + ((hi ^ sxv) * 8)]);
        bf16x8 v1 = *reinterpret_cast<const bf16x8*>(&vbase[(16 + lo) * 32 + ((hi ^ sxv) * 8)]);
        bf16x8 v2 = *reinterpret_cast<const bf16x8*>(&vbase[(32 + lo) * 32 + ((hi ^ sxv) * 8)]);
        bf16x8 v3 = *reinterpret_cast<const bf16x8*>(&vbase[(48 + lo) * 32 + ((hi ^ sxv) * 8)]);
        c0 = MFMA_B16(pa, v0, c0);
        c1 = MFMA_B16(pa, v1, c1);
        c2 = MFMA_B16(pa, v2, c2);
        c3 = MFMA_B16(pa, v3, c3);
      }
      // attn stores from Ps (bf16<<16 -> f32), youngest vm ops of the tile
      {
        float* arow = abase + (size_t)srow * NS + t * 32 + schunk * 8;
        bf16x8 q0 = *reinterpret_cast<const bf16x8*>(&psw[srow * 40 + schunk * 8]);
        f32x4 o0, o1;
#pragma unroll
        for (int j = 0; j < 4; ++j) { o0[j] = bf2f((u16)q0[j]); o1[j] = bf2f((u16)q0[j + 4]); }
        *reinterpret_cast<f32x4*>(arow + 0) = o0;
        *reinterpret_cast<f32x4*>(arow + 4) = o1;
      }
      asm volatile("s_waitcnt vmcnt(10)" ::: "memory");  // st(t+1) done; st(t+2)+mask+stores float
      __builtin_amdgcn_s_barrier();
      asm volatile("" ::: "memory");
      cur = (cur + 1 == 3) ? 0 : cur + 1;
    }
  }

  // ctx epilogue (P normalized -> cacc final)
#define CTXW(cv, ct)                                                                      \
  {                                                                                       \
    ctx[((size_t)b * NS + qr0 + rbase + 0) * 1024 + h * 64 + (ct)*16 + lo] = f2bf(cv[0]); \
    ctx[((size_t)b * NS + qr0 + rbase + 1) * 1024 + h * 64 + (ct)*16 + lo] = f2bf(cv[1]); \
    ctx[((size_t)b * NS + qr0 + rbase + 2) * 1024 + h * 64 + (ct)*16 + lo] = f2bf(cv[2]); \
    ctx[((size_t)b * NS + qr0 + rbase + 3) * 1024 + h * 64 + (ct)*16 + lo] = f2bf(cv[3]); \
  }
  CTXW(c0, 0) CTXW(c1, 1) CTXW(c2, 2) CTXW(c3, 3)
#undef CTXW
#undef STAGE_KT
#undef STAGE_VT
}

extern "C" void kernel_launch(void* const* d_in, const int* in_sizes, int n_in,
                              void* d_out, int out_size, void* d_ws, size_t ws_size,
                              hipStream_t stream) {
  const float* Q = (const float*)d_in[0];
  const float* K = (const float*)d_in[1];
  const float* V = (const float*)d_in[2];
  const u32* mask = (const u32*)d_in[3];
  const float* wq = (const float*)d_in[4];
  const float* bq = (const float*)d_in[5];
  const float* wk = (const float*)d_in[6];
  const float* bk = (const float*)d_in[7];
  const float* wv = (const float*)d_in[8];
  const float* bv = (const float*)d_in[9];
  const float* wo = (const float*)d_in[10];
  const float* bo = (const float*)d_in[11];
  float* out = (float*)d_out;
  float* attn = out + (size_t)NB * NS * NDM;

  char* ws = (char*)d_ws;
  u16* Qb  = (u16*)(ws + 0);
  u16* Kb  = (u16*)(ws + 8388608);
  u16* Vb  = (u16*)(ws + 16777216);
  u16* wqT = (u16*)(ws + 25165824);
  u16* wkT = (u16*)(ws + 27262976);
  u16* wvT = (u16*)(ws + 29360128);
  u16* woT = (u16*)(ws + 31457280);
  u16* qhd = (u16*)(ws + 33554432);
  u16* khd = (u16*)(ws + 41943040);
  u16* vTd = (u16*)(ws + 50331648);
  u16* ctx = (u16*)(ws + 58720256);
  u32* mbits = (u32*)(ws + 0);

  cast3_bf16<<<12288, 256, 0, stream>>>(Q, K, V, Qb, Kb, Vb);
  TW4 tw;
  tw.in[0] = wq; tw.in[1] = wk; tw.in[2] = wv; tw.in[3] = wo;
  tw.out[0] = wqT; tw.out[1] = wkT; tw.out[2] = wvT; tw.out[3] = woT;
  transpose_w4<<<dim3(32, 32, 4), 256, 0, stream>>>(tw);

  GArgs gq = {Qb, wqT, bq, (void*)qhd, 0, 0.125f};   // fold 1/sqrt(dk) into q
  GArgs gk = {Kb, wkT, bk, (void*)khd, 0, 1.0f};
  GArgs gv = {Vb, wvT, bv, (void*)vTd, 1, 1.0f};
  gemm_bt<<<dim3(32, 8, 3), 256, 0, stream>>>(gq, gk, gv);

  mask2bits<<<1024, 256, 0, stream>>>(mask, mbits);

  attn_kernel<<<1024, 256, 0, stream>>>(qhd, khd, vTd, mbits, attn, ctx);

  GArgs go = {ctx, woT, bo, d_out, 2, 1.0f};
  gemm_bt<<<dim3(32, 8, 1), 256, 0, stream>>>(go, go, go);
}

// Round 13
// 328.938 us; speedup vs baseline: 1.1046x; 1.0304x over previous
//
#include <hip/hip_runtime.h>

typedef unsigned short u16;
typedef unsigned int u32;
typedef unsigned long long u64;
typedef __attribute__((ext_vector_type(8))) short bf16x8;
typedef __attribute__((ext_vector_type(4))) float f32x4;

#define NB 2
#define NS 2048
#define NDM 1024
#define NH 16

#define MFMA_B16(a, b, c) __builtin_amdgcn_mfma_f32_16x16x32_bf16(a, b, c, 0, 0, 0)

__device__ __forceinline__ u16 f2bf(float f) {
  union { float f; unsigned u; } v; v.f = f;
  return (u16)((v.u + 0x7fffu + ((v.u >> 16) & 1u)) >> 16);
}
__device__ __forceinline__ float bf2f(u16 h) {
  union { float f; unsigned u; } v; v.u = ((u32)h) << 16; return v.f;
}

// fused cast of Q,K,V -> bf16 (3 x 1048576 float4 quads)
__global__ __launch_bounds__(256) void cast3_bf16(const float* __restrict__ a,
                                                  const float* __restrict__ b,
                                                  const float* __restrict__ c,
                                                  u16* __restrict__ oa, u16* __restrict__ ob,
                                                  u16* __restrict__ oc) {
  int i = blockIdx.x * 256 + threadIdx.x;
  const float* src; u16* dst; int j;
  if (i < 1048576) { src = a; dst = oa; j = i; }
  else if (i < 2097152) { src = b; dst = ob; j = i - 1048576; }
  else { src = c; dst = oc; j = i - 2097152; }
  const float4 v = reinterpret_cast<const float4*>(src)[j];
  ushort4 o; o.x = f2bf(v.x); o.y = f2bf(v.y); o.z = f2bf(v.z); o.w = f2bf(v.w);
  reinterpret_cast<ushort4*>(dst)[j] = o;
}

// fused transpose of the 4 weight matrices: f32 [1024][1024] -> bf16 transposed
struct TW4 { const float* in[4]; u16* out[4]; };
__global__ __launch_bounds__(256) void transpose_w4(TW4 tw) {
  __shared__ float tile[32][33];
  const float* in = tw.in[blockIdx.z];
  u16* out = tw.out[blockIdx.z];
  int bx = blockIdx.x, by = blockIdx.y;
  int x = threadIdx.x & 31, y0 = threadIdx.x >> 5;
#pragma unroll
  for (int i = 0; i < 4; i++) {
    int y = y0 + i * 8;
    tile[y][x] = in[(by * 32 + y) * NDM + bx * 32 + x];
  }
  __syncthreads();
#pragma unroll
  for (int i = 0; i < 4; i++) {
    int y = y0 + i * 8;
    out[(bx * 32 + y) * NDM + by * 32 + x] = f2bf(tile[x][y]);
  }
}

// ---- mask [B,S,S] -> bitmask, 1 bit/col ----
__global__ __launch_bounds__(256) void mask2bits(const u32* __restrict__ mask, u32* __restrict__ mb) {
  int idx = blockIdx.x * 256 + threadIdx.x;
  u32 mw0 = mask[threadIdx.x & 63];
  bool floatmode = (__ballot(mw0 == 0x3F800000u) != 0ull);
  bool bytemode = !floatmode && (__ballot((mw0 >> 8) != 0u) != 0ull);
  int row = idx >> 6;
  int wword = idx & 63;
  u32 bits = 0;
  if (!bytemode) {
    const uint4* p = reinterpret_cast<const uint4*>(mask + (size_t)row * 2048 + wword * 32);
#pragma unroll
    for (int i = 0; i < 8; i++) {
      uint4 v = p[i];
      bits |= (v.x ? 1u : 0u) << (i * 4 + 0);
      bits |= (v.y ? 1u : 0u) << (i * 4 + 1);
      bits |= (v.z ? 1u : 0u) << (i * 4 + 2);
      bits |= (v.w ? 1u : 0u) << (i * 4 + 3);
    }
  } else {
    const uint4* p = reinterpret_cast<const uint4*>(
        reinterpret_cast<const unsigned char*>(mask) + (size_t)row * 2048 + wword * 32);
#pragma unroll
    for (int i = 0; i < 2; i++) {
      uint4 v = p[i];
      u32 wsv[4] = {v.x, v.y, v.z, v.w};
#pragma unroll
      for (int j = 0; j < 4; j++)
#pragma unroll
        for (int kq = 0; kq < 4; kq++)
          bits |= ((((wsv[j] >> (kq * 8)) & 0xffu) != 0u) ? 1u : 0u) << (i * 16 + j * 4 + kq);
    }
  }
  mb[idx] = bits;
}

// ---- 128x128-tile bf16 GEMM, B^T layout ----
struct GArgs { const u16* X; const u16* W; const float* bias; void* out; int mode; float scale; };

__global__ __launch_bounds__(256, 2) void gemm_bt(GArgs g0, GArgs g1, GArgs g2) {
  GArgs ga = (blockIdx.z == 0) ? g0 : (blockIdx.z == 1 ? g1 : g2);
  const int K = 1024, N = 1024;
  __shared__ u16 As[128 * 32];
  __shared__ u16 Bs[128 * 32];
  const int t = threadIdx.x, w = t >> 6, l = t & 63;
  const int m0 = blockIdx.x * 128, n0 = blockIdx.y * 128;
  const int wm = (w >> 1) * 64, wn = (w & 1) * 64;
  const f32x4 fz = {0.f, 0.f, 0.f, 0.f};
  f32x4 acc[4][4];
#pragma unroll
  for (int i = 0; i < 4; i++)
#pragma unroll
    for (int j = 0; j < 4; j++) acc[i][j] = fz;

  for (int k0 = 0; k0 < K; k0 += 32) {
#pragma unroll
    for (int i = 0; i < 2; i++) {
      int idx = i * 256 + w * 64 + l;
      int r = idx >> 2, c = (idx & 3) * 8;
      __builtin_amdgcn_global_load_lds(
          reinterpret_cast<const unsigned*>(ga.X + (size_t)(m0 + r) * K + k0 + c),
          reinterpret_cast<unsigned*>(&As[(i * 256 + w * 64) * 8]), 16, 0, 0);
      __builtin_amdgcn_global_load_lds(
          reinterpret_cast<const unsigned*>(ga.W + (size_t)(n0 + r) * K + k0 + c),
          reinterpret_cast<unsigned*>(&Bs[(i * 256 + w * 64) * 8]), 16, 0, 0);
    }
    __syncthreads();
    bf16x8 af[4], bfr[4];
#pragma unroll
    for (int mt = 0; mt < 4; mt++)
      af[mt] = *reinterpret_cast<const bf16x8*>(&As[(wm + mt * 16 + (l & 15)) * 32 + (l >> 4) * 8]);
#pragma unroll
    for (int nt = 0; nt < 4; nt++)
      bfr[nt] = *reinterpret_cast<const bf16x8*>(&Bs[(wn + nt * 16 + (l & 15)) * 32 + (l >> 4) * 8]);
#pragma unroll
    for (int mt = 0; mt < 4; mt++)
#pragma unroll
      for (int nt = 0; nt < 4; nt++)
        acc[mt][nt] = MFMA_B16(af[mt], bfr[nt], acc[mt][nt]);
    __syncthreads();
  }

#pragma unroll
  for (int nt = 0; nt < 4; nt++) {
    int n = n0 + wn + nt * 16 + (l & 15);
    float bias = ga.bias[n];
#pragma unroll
    for (int mt = 0; mt < 4; mt++) {
      int mb = m0 + wm + mt * 16 + ((l >> 4) << 2);
#pragma unroll
      for (int r = 0; r < 4; r++) {
        int m = mb + r;
        float v = (acc[mt][nt][r] + bias) * ga.scale;
        if (ga.mode == 2) {
          reinterpret_cast<float*>(ga.out)[(size_t)m * N + n] = v;
        } else {
          int b = m >> 11, s = m & 2047, h = n >> 6, d = n & 63;
          if (ga.mode == 0)
            reinterpret_cast<u16*>(ga.out)[(((size_t)(b * NH + h) * NS + s) << 6) + d] = f2bf(v);
          else
            reinterpret_cast<u16*>(ga.out)[((size_t)(b * NH + h) * 64 + d) * NS + s] = f2bf(v);
        }
      }
    }
  }
}

// ---- attention: R9 structure + DEFERRED PV (T15 at LDS granularity).
// Pass 2 tile t: {stage(t+1); mask(t+1); PV(t-1)+stores(t-1) from Ps/Vs (no wait);
// QK(t)+exp -> Ps[t&1]; vmcnt(6); barrier}. The exp->Ps->PV serial chain is broken:
// PV and stores overlap QK's ds_read/MFMA/exp. Ks dbuf, Vs triple-buf (staged t,
// consumed t+2), Ps per-wave dbuf. LDS = 8K+12K+10K = 30720 B -> 4 blocks/CU. ----
__global__ __launch_bounds__(256, 4) void attn_kernel(
    const u16* __restrict__ qh, const u16* __restrict__ kh, const u16* __restrict__ vT,
    const u32* __restrict__ mb, float* __restrict__ attn, u16* __restrict__ ctx) {
  __shared__ u16 Ks[2][32 * 64];
  __shared__ u16 Vs[3][64 * 32];
  __shared__ u16 Ps[4][2][16 * 40];
  const int tid = threadIdx.x, w = tid >> 6, l = tid & 63;
  int id = blockIdx.x;
  int wgid = (id & 7) * 128 + (id >> 3);   // XCD-chunked bijective swizzle (1024 % 8 == 0)
  int qt = wgid & 31, pr = wgid >> 5;
  int h = pr & 15, b = pr >> 4;
  const size_t head = (size_t)b * NH + h;
  const u16* qp = qh + head * NS * 64;
  const u16* kp = kh + head * NS * 64;
  const u16* vp = vT + head * 64 * NS;
  const int qr0 = qt * 64 + w * 16;
  const int lo = l & 15, hi = l >> 4;
  const int rbase = hi << 2;
  const f32x4 fz = {0.f, 0.f, 0.f, 0.f};

  bf16x8 aq0, aq1;
  {
    const u16* p = qp + (size_t)(qr0 + lo) * 64 + hi * 8;
    aq0 = *reinterpret_cast<const bf16x8*>(p);
    aq1 = *reinterpret_cast<const bf16x8*>(p + 32);
  }
  const u32* mrow = mb + ((size_t)b * NS + qr0 + rbase) * 64;  // 64 u32 words per row

  // staging sources, pre-swizzled (involution: same XOR applied on ds_read)
  const int k_row = tid >> 3, k_slot = tid & 7;
  const u16* ksrc0 = kp + (size_t)k_row * 64 + ((k_slot ^ (k_row & 7)) * 8);
  const int v_dv = tid >> 2, v_slot = tid & 3;
  const u16* vsrc0 = vp + (size_t)v_dv * NS + ((v_slot ^ ((v_dv >> 1) & 3)) * 8);
  const int sxk = lo & 7;
  const int sxv = (lo >> 1) & 3;

#define STAGE_KT(tt, bi)                                                                \
  __builtin_amdgcn_global_load_lds(                                                     \
      reinterpret_cast<const unsigned*>(ksrc0 + (size_t)(tt) * 2048),                   \
      reinterpret_cast<unsigned*>(&Ks[bi][w * 512]), 16, 0, 0);
#define STAGE_VT(tt, bi)                                                                \
  __builtin_amdgcn_global_load_lds(                                                     \
      reinterpret_cast<const unsigned*>(vsrc0 + (size_t)(tt) * 32),                     \
      reinterpret_cast<unsigned*>(&Vs[bi][w * 512]), 16, 0, 0);

// QK for tile buffer kb -> s0 (cols 0..15), s1 (cols 16..31)
#define QK_TILE(kb, s0, s1)                                                             \
  {                                                                                     \
    const u16* kbase = &Ks[kb][0];                                                      \
    bf16x8 b00 = *reinterpret_cast<const bf16x8*>(&kbase[(lo) * 64 + ((hi ^ sxk) * 8)]);        \
    bf16x8 b01 = *reinterpret_cast<const bf16x8*>(&kbase[(lo) * 64 + (((4 + hi) ^ sxk) * 8)]);  \
    bf16x8 b10 = *reinterpret_cast<const bf16x8*>(&kbase[(16 + lo) * 64 + ((hi ^ sxk) * 8)]);   \
    bf16x8 b11 = *reinterpret_cast<const bf16x8*>(&kbase[(16 + lo) * 64 + (((4 + hi) ^ sxk) * 8)]); \
    s0 = MFMA_B16(aq1, b01, MFMA_B16(aq0, b00, fz));                                    \
    s1 = MFMA_B16(aq1, b11, MFMA_B16(aq0, b10, fz));                                    \
  }
// exp + normalize + write Ps buffer pb
#define EXP_PS(pb, s0, s1)                                                              \
  {                                                                                     \
    u16* pc = &Ps[w][pb][0];                                                            \
    float p;                                                                            \
    p = ((mc0 >> lo) & 1u) ? 0.f : __expf(s0[0]) * rs0; pc[(rbase + 0) * 40 + lo] = f2bf(p); \
    p = ((mc1 >> lo) & 1u) ? 0.f : __expf(s0[1]) * rs1; pc[(rbase + 1) * 40 + lo] = f2bf(p); \
    p = ((mc2 >> lo) & 1u) ? 0.f : __expf(s0[2]) * rs2; pc[(rbase + 2) * 40 + lo] = f2bf(p); \
    p = ((mc3 >> lo) & 1u) ? 0.f : __expf(s0[3]) * rs3; pc[(rbase + 3) * 40 + lo] = f2bf(p); \
    int bit1 = 16 + lo;                                                                 \
    p = ((mc0 >> bit1) & 1u) ? 0.f : __expf(s1[0]) * rs0; pc[(rbase + 0) * 40 + 16 + lo] = f2bf(p); \
    p = ((mc1 >> bit1) & 1u) ? 0.f : __expf(s1[1]) * rs1; pc[(rbase + 1) * 40 + 16 + lo] = f2bf(p); \
    p = ((mc2 >> bit1) & 1u) ? 0.f : __expf(s1[2]) * rs2; pc[(rbase + 2) * 40 + 16 + lo] = f2bf(p); \
    p = ((mc3 >> bit1) & 1u) ? 0.f : __expf(s1[3]) * rs3; pc[(rbase + 3) * 40 + 16 + lo] = f2bf(p); \
  }
// deferred PV + attn stores for tile tt (Ps buffer pb, Vs buffer vb)
#define PV_STORES(tt, pb, vb)                                                           \
  {                                                                                     \
    u16* pp = &Ps[w][pb][0];                                                            \
    const u16* vbase = &Vs[vb][0];                                                      \
    bf16x8 pa = *reinterpret_cast<const bf16x8*>(&pp[lo * 40 + hi * 8]);                \
    bf16x8 v0 = *reinterpret_cast<const bf16x8*>(&vbase[(lo) * 32 + ((hi ^ sxv) * 8)]);        \
    bf16x8 v1 = *reinterpret_cast<const bf16x8*>(&vbase[(16 + lo) * 32 + ((hi ^ sxv) * 8)]);   \
    bf16x8 v2 = *reinterpret_cast<const bf16x8*>(&vbase[(32 + lo) * 32 + ((hi ^ sxv) * 8)]);   \
    bf16x8 v3 = *reinterpret_cast<const bf16x8*>(&vbase[(48 + lo) * 32 + ((hi ^ sxv) * 8)]);   \
    c0 = MFMA_B16(pa, v0, c0);                                                          \
    c1 = MFMA_B16(pa, v1, c1);                                                          \
    c2 = MFMA_B16(pa, v2, c2);                                                          \
    c3 = MFMA_B16(pa, v3, c3);                                                          \
    float* arow = abase + (size_t)srow * NS + (tt) * 32 + schunk * 8;                   \
    bf16x8 q0 = *reinterpret_cast<const bf16x8*>(&pp[srow * 40 + schunk * 8]);          \
    f32x4 o0, o1;                                                                       \
    _Pragma("unroll") for (int j = 0; j < 4; ++j) {                                     \
      o0[j] = bf2f((u16)q0[j]); o1[j] = bf2f((u16)q0[j + 4]);                           \
    }                                                                                   \
    *reinterpret_cast<f32x4*>(arow + 0) = o0;                                           \
    *reinterpret_cast<f32x4*>(arow + 4) = o1;                                           \
  }

  float rs0 = 0.f, rs1 = 0.f, rs2 = 0.f, rs3 = 0.f;

  // ================= pass 1: row sums (unchanged from R9) =================
  u32 mc0 = mrow[0], mc1 = mrow[64], mc2 = mrow[128], mc3 = mrow[192];
  STAGE_KT(0, 0);
  asm volatile("s_waitcnt vmcnt(0)" ::: "memory");
  __builtin_amdgcn_s_barrier();
  asm volatile("" ::: "memory");

  for (int t = 0; t < 64; ++t) {
    STAGE_KT(t + 1, (t + 1) & 1);
    u32 mn0 = mrow[t + 1], mn1 = mrow[65 + t], mn2 = mrow[129 + t], mn3 = mrow[193 + t];
    asm volatile("" ::: "memory");
    f32x4 s0, s1;
    QK_TILE(t & 1, s0, s1);
    rs0 += ((mc0 >> lo) & 1u) ? 0.f : __expf(s0[0]);
    rs1 += ((mc1 >> lo) & 1u) ? 0.f : __expf(s0[1]);
    rs2 += ((mc2 >> lo) & 1u) ? 0.f : __expf(s0[2]);
    rs3 += ((mc3 >> lo) & 1u) ? 0.f : __expf(s0[3]);
    int bit1 = 16 + lo;
    rs0 += ((mc0 >> bit1) & 1u) ? 0.f : __expf(s1[0]);
    rs1 += ((mc1 >> bit1) & 1u) ? 0.f : __expf(s1[1]);
    rs2 += ((mc2 >> bit1) & 1u) ? 0.f : __expf(s1[2]);
    rs3 += ((mc3 >> bit1) & 1u) ? 0.f : __expf(s1[3]);
    mc0 = mn0; mc1 = mn1; mc2 = mn2; mc3 = mn3;
    asm volatile("s_waitcnt vmcnt(4)" ::: "memory");   // drains stage(t+1); mask(t+1) floats
    __builtin_amdgcn_s_barrier();
    asm volatile("" ::: "memory");
  }

  {
    float v;
    v = rs0; v += __shfl_xor(v, 1); v += __shfl_xor(v, 2); v += __shfl_xor(v, 4); v += __shfl_xor(v, 8);
    rs0 = 1.f / fmaxf(v, 1e-30f);
    v = rs1; v += __shfl_xor(v, 1); v += __shfl_xor(v, 2); v += __shfl_xor(v, 4); v += __shfl_xor(v, 8);
    rs1 = 1.f / fmaxf(v, 1e-30f);
    v = rs2; v += __shfl_xor(v, 1); v += __shfl_xor(v, 2); v += __shfl_xor(v, 4); v += __shfl_xor(v, 8);
    rs2 = 1.f / fmaxf(v, 1e-30f);
    v = rs3; v += __shfl_xor(v, 1); v += __shfl_xor(v, 2); v += __shfl_xor(v, 4); v += __shfl_xor(v, 8);
    rs3 = 1.f / fmaxf(v, 1e-30f);
  }

  // ================= pass 2: deferred-PV pipeline =================
  f32x4 c0 = fz, c1 = fz, c2 = fz, c3 = fz;
  float* abase = attn + (head * NS + qr0) * NS;
  const int srow = l >> 2, schunk = l & 3;

  mc0 = mrow[0]; mc1 = mrow[64]; mc2 = mrow[128]; mc3 = mrow[192];
  STAGE_KT(0, 0);
  STAGE_VT(0, 0);
  asm volatile("s_waitcnt vmcnt(0)" ::: "memory");
  __builtin_amdgcn_s_barrier();
  asm volatile("" ::: "memory");

  // ---- peeled tile 0 (no deferred work yet) ----
  {
    STAGE_KT(1, 1);
    STAGE_VT(1, 1);
    u32 mn0 = mrow[1], mn1 = mrow[65], mn2 = mrow[129], mn3 = mrow[193];
    asm volatile("" ::: "memory");
    f32x4 s0, s1;
    QK_TILE(0, s0, s1);
    EXP_PS(0, s0, s1);
    mc0 = mn0; mc1 = mn1; mc2 = mn2; mc3 = mn3;
    asm volatile("s_waitcnt vmcnt(4)" ::: "memory");   // drains stage(1); mask(1) floats
    __builtin_amdgcn_s_barrier();
    asm volatile("" ::: "memory");
  }

  // ---- main loop t = 1..63 ----
  for (int t = 1; t < 64; ++t) {
    if (t + 1 < 64) {
      int vb2 = (t + 1) % 3;
      STAGE_KT(t + 1, (t + 1) & 1);
      STAGE_VT(t + 1, vb2);
    }
    u32 mn0 = mrow[t + 1], mn1 = mrow[65 + t], mn2 = mrow[129 + t], mn3 = mrow[193 + t];
    asm volatile("" ::: "memory");
    // deferred PV + attn stores for tile t-1 (Ps/Vs ready, no wait)
    PV_STORES(t - 1, (t - 1) & 1, (t - 1) % 3);
    // QK(t) + exp -> Ps[t&1]
    f32x4 s0, s1;
    QK_TILE(t & 1, s0, s1);
    EXP_PS(t & 1, s0, s1);
    mc0 = mn0; mc1 = mn1; mc2 = mn2; mc3 = mn3;
    asm volatile("s_waitcnt vmcnt(6)" ::: "memory");   // drains stages; mask4+stores2 float
    __builtin_amdgcn_s_barrier();
    asm volatile("" ::: "memory");
  }

  // ---- epilogue: deferred work for tile 63 ----
  PV_STORES(63, 1, 0);

  // ctx epilogue (P normalized -> cacc final)
#define CTXW(cv, ct)                                                                      \
  {                                                                                       \
    ctx[((size_t)b * NS + qr0 + rbase + 0) * 1024 + h * 64 + (ct)*16 + lo] = f2bf(cv[0]); \
    ctx[((size_t)b * NS + qr0 + rbase + 1) * 1024 + h * 64 + (ct)*16 + lo] = f2bf(cv[1]); \
    ctx[((size_t)b * NS + qr0 + rbase + 2) * 1024 + h * 64 + (ct)*16 + lo] = f2bf(cv[2]); \
    ctx[((size_t)b * NS + qr0 + rbase + 3) * 1024 + h * 64 + (ct)*16 + lo] = f2bf(cv[3]); \
  }
  CTXW(c0, 0) CTXW(c1, 1) CTXW(c2, 2) CTXW(c3, 3)
#undef CTXW
#undef STAGE_KT
#undef STAGE_VT
#undef QK_TILE
#undef EXP_PS
#undef PV_STORES
}

extern "C" void kernel_launch(void* const* d_in, const int* in_sizes, int n_in,
                              void* d_out, int out_size, void* d_ws, size_t ws_size,
                              hipStream_t stream) {
  const float* Q = (const float*)d_in[0];
  const float* K = (const float*)d_in[1];
  const float* V = (const float*)d_in[2];
  const u32* mask = (const u32*)d_in[3];
  const float* wq = (const float*)d_in[4];
  const float* bq = (const float*)d_in[5];
  const float* wk = (const float*)d_in[6];
  const float* bk = (const float*)d_in[7];
  const float* wv = (const float*)d_in[8];
  const float* bv = (const float*)d_in[9];
  const float* wo = (const float*)d_in[10];
  const float* bo = (const float*)d_in[11];
  float* out = (float*)d_out;
  float* attn = out + (size_t)NB * NS * NDM;

  char* ws = (char*)d_ws;
  u16* Qb  = (u16*)(ws + 0);
  u16* Kb  = (u16*)(ws + 8388608);
  u16* Vb  = (u16*)(ws + 16777216);
  u16* wqT = (u16*)(ws + 25165824);
  u16* wkT = (u16*)(ws + 27262976);
  u16* wvT = (u16*)(ws + 29360128);
  u16* woT = (u16*)(ws + 31457280);
  u16* qhd = (u16*)(ws + 33554432);
  u16* khd = (u16*)(ws + 41943040);
  u16* vTd = (u16*)(ws + 50331648);
  u16* ctx = (u16*)(ws + 58720256);
  u32* mbits = (u32*)(ws + 0);

  cast3_bf16<<<12288, 256, 0, stream>>>(Q, K, V, Qb, Kb, Vb);
  TW4 tw;
  tw.in[0] = wq; tw.in[1] = wk; tw.in[2] = wv; tw.in[3] = wo;
  tw.out[0] = wqT; tw.out[1] = wkT; tw.out[2] = wvT; tw.out[3] = woT;
  transpose_w4<<<dim3(32, 32, 4), 256, 0, stream>>>(tw);

  GArgs gq = {Qb, wqT, bq, (void*)qhd, 0, 0.125f};   // fold 1/sqrt(dk) into q
  GArgs gk = {Kb, wkT, bk, (void*)khd, 0, 1.0f};
  GArgs gv = {Vb, wvT, bv, (void*)vTd, 1, 1.0f};
  gemm_bt<<<dim3(32, 8, 3), 256, 0, stream>>>(gq, gk, gv);

  mask2bits<<<1024, 256, 0, stream>>>(mask, mbits);

  attn_kernel<<<1024, 256, 0, stream>>>(qhd, khd, vTd, mbits, attn, ctx);

  GArgs go = {ctx, woT, bo, d_out, 2, 1.0f};
  gemm_bt<<<dim3(32, 8, 1), 256, 0, stream>>>(go, go, go);
}